// Round 5
// baseline (281.995 us; speedup 1.0000x reference)
//
#include <hip/hip_runtime.h>
#include <stdint.h>

// Problem: out[M=2048(size_out), N=8192(batch)] = W[K,M]^T @ X[N,K]^T
//   out[m,n] = sum_k W[k,m] * X[n,k]
#define M_DIM 2048
#define N_DIM 8192
#define K_DIM 2048

typedef _Float16 f16x8 __attribute__((ext_vector_type(8)));
typedef _Float16 f16x4 __attribute__((ext_vector_type(4)));
typedef float    f32x4 __attribute__((ext_vector_type(4)));

// ---------------- fused prep: cvt X (blocks 0..8191) + transpose W (8192..12287) ----------------

__global__ __launch_bounds__(256) void prep(const float* __restrict__ X,
                                            const float* __restrict__ W,
                                            _Float16* __restrict__ Xb,
                                            _Float16* __restrict__ Wt) {
    __shared__ float tile[32][33];
    int b = blockIdx.x;
    if (b < 8192) {
        size_t i = ((size_t)b * 256 + threadIdx.x) * 8;
        float4 a = *(const float4*)(X + i);
        float4 c = *(const float4*)(X + i + 4);
        f16x8 h;
        h[0] = (_Float16)a.x; h[1] = (_Float16)a.y; h[2] = (_Float16)a.z; h[3] = (_Float16)a.w;
        h[4] = (_Float16)c.x; h[5] = (_Float16)c.y; h[6] = (_Float16)c.z; h[7] = (_Float16)c.w;
        *(f16x8*)(Xb + i) = h;
    } else {
        b -= 8192;
        const int m0 = (b & 63) * 32;
        const int k0 = (b >> 6) * 32;
        const int tx = threadIdx.x & 31;
        const int ty = threadIdx.x >> 5;
#pragma unroll
        for (int i = 0; i < 32; i += 8)
            tile[ty + i][tx] = W[(size_t)(k0 + ty + i) * M_DIM + m0 + tx];
        __syncthreads();
        const int ml = threadIdx.x >> 3;
        const int kg = (threadIdx.x & 7) * 4;
        f16x4 v;
#pragma unroll
        for (int j = 0; j < 4; ++j) v[j] = (_Float16)tile[kg + j][ml];
        *(f16x4*)(Wt + (size_t)(m0 + ml) * K_DIM + k0 + kg) = v;
    }
}

// ---------------- 256x256 f16 GEMM: A direct-from-L2 to registers, B-only LDS ----------------
//
// R1-R4 all pinned at ~5300 cyc/K-tile = serial(LDS 2300 + DMA 500 + MFMA 2480):
// with 2 waves/SIMD the LDS-read windows and MFMA windows alternate instead of
// overlapping. Fix: remove A from LDS. A (Wt) fragments load global->VGPR
// directly: bm panel = 1MB, XCD-L2-resident (XCD swizzle), 4 wn-waves read
// identical addresses (L1 hits), each instr = 16 rows x 64B segments.
// LDS now holds only B: 4 half-slot ring x 16KB (256 rows x 64B, 32 k each).
// B swizzle/staging = byte-identical to the R2-R4 hardware-verified scheme
// (slot s of row r holds chunk s ^ ((r>>1)&3); 0 bank conflicts measured).
//
// Steps: 64 of K=32. Step s: uses af regs loaded at s-1, B half-slot s&3
// (staged at s-2). Issues exactly 10 VMEM ops in order [8 A-loads for s+1,
// 2 B-stages for s+2] -> vmcnt(10) at step top == "all ops >=2 steps old
// retired" (counted wait, never a drain). af double-buffered afA/afB by step
// parity (static indexing). 32 MFMA per step (8mi x 4ni, K=32).

__device__ __forceinline__ void load_to_lds16(const void* g, void* l) {
    __builtin_amdgcn_global_load_lds(
        (__attribute__((address_space(1))) void*)(uintptr_t)g,
        (__attribute__((address_space(3))) void*)l,
        16, 0, 0);
}

template <int HS>
__device__ __forceinline__ void stepK(const char* lds, int pB,
                                      f16x8 (&afU)[8], f16x8 (&afL)[8],
                                      const _Float16* pa, int koffA,
                                      const _Float16* sb, char* db, int koffB,
                                      f32x4 (&acc)[8][4]) {
    __builtin_amdgcn_s_barrier();
    asm volatile("s_waitcnt vmcnt(10)" ::: "memory");   // B stage for HS (s-2) retired
    f16x8 bf[4];
#pragma unroll
    for (int ni = 0; ni < 4; ++ni)
        bf[ni] = *(const f16x8*)(lds + HS * 16384 + ni * 1024 + pB);
    // issue next-step A fragments (8 x global_load_dwordx4 -> regs)
#pragma unroll
    for (int mi = 0; mi < 8; ++mi)
        afL[mi] = *(const f16x8*)(pa + (size_t)mi * 16 * K_DIM + koffA);
    // issue B stage for step s+2 into half-slot (HS+2)&3
    constexpr int DS = ((HS + 2) & 3) * 16384;
    load_to_lds16(sb + koffB, db + DS);
    load_to_lds16(sb + (size_t)128 * K_DIM + koffB, db + DS + 8192);
    asm volatile("s_waitcnt lgkmcnt(0)" ::: "memory");  // bf in regs (compiler adds af wait)
    __builtin_amdgcn_sched_barrier(0);
    __builtin_amdgcn_s_setprio(1);
#pragma unroll
    for (int mi = 0; mi < 8; ++mi)
#pragma unroll
        for (int ni = 0; ni < 4; ++ni)
            acc[mi][ni] = __builtin_amdgcn_mfma_f32_16x16x32_f16(afU[mi], bf[ni], acc[mi][ni], 0, 0, 0);
    __builtin_amdgcn_s_setprio(0);
}

// A = Wt [M,K] f16 (K-contiguous), B = Xb [N,K] f16 (K-contiguous), C [M,N] fp32
__global__ __launch_bounds__(512, 2) void gemm_f16_256(const _Float16* __restrict__ A,
                                                       const _Float16* __restrict__ B,
                                                       float* __restrict__ C) {
    extern __shared__ char lds[];          // 4 x 16KB B half-slots = 64KB

    const int tid  = threadIdx.x;
    const int wave = tid >> 6;
    const int lane = tid & 63;
    const int lm = lane & 15, kq = lane >> 4;
    const int wm = wave >> 2, wn = wave & 3;   // 2x4 wave grid, each 128x64 of C

    // XCD swizzle: XCD x owns bm = x (1MB A panel L2-resident) x all 32 bn
    const int bid = ((blockIdx.x & 7) << 5) | (blockIdx.x >> 3);
    const int bm = bid >> 5;               // 0..7
    const int bn = bid & 31;               // 0..31

    // B staging source (per-thread): row = tid>>2 (64B rows), inverse-swizzled chunk
    const int srow = tid >> 2;                            // 0..127
    const int cg   = ((tid & 3) ^ ((tid >> 3) & 3)) * 8;  // f16 elems within 32-k row
    const _Float16* sb = B + (size_t)(bn * 256 + srow) * K_DIM + cg;
    char* db = lds + wave * 1024;          // + halfslot*16384 (+8192 for issue 1)

    // B fragment read offset: row rb = wn*64 + ni*16 + lm, chunk kq at slot kq^((rb>>1)&3)
    const int swz = (kq ^ ((lm >> 1) & 3)) * 16;
    const int pB  = wn * 4096 + lm * 64 + swz;   // + halfslot*16384 + ni*1024

    // A direct per-lane fragment pointer: row = bm*256 + wm*128 + mi*16 + lm, k = s*32 + kq*8
    const _Float16* pa = A + (size_t)(bm * 256 + wm * 128 + lm) * K_DIM + kq * 8;

    f32x4 acc[8][4] = {};
    f16x8 afA[8], afB[8];

    // prologue (VMEM order: 2 stage hs0, 2 stage hs1, 8 afA) = 12 ops
    load_to_lds16(sb,                        db);
    load_to_lds16(sb + (size_t)128 * K_DIM,  db + 8192);
    load_to_lds16(sb + 32,                       db + 16384);
    load_to_lds16(sb + (size_t)128 * K_DIM + 32, db + 16384 + 8192);
#pragma unroll
    for (int mi = 0; mi < 8; ++mi)
        afA[mi] = *(const f16x8*)(pa + (size_t)mi * 16 * K_DIM);

    // 64 steps of K=32; half-slots cycle 0,1,2,3 per 2 K-tiles.
    // koffA for step s loads k-chunk s+1; koffB stages chunk s+2 (&63 wraps tail
    // to valid-but-dead addresses/slots: slot (s+2)&3 was last read at s-2).
#pragma unroll 1
    for (int t2 = 0; t2 < 16; ++t2) {
        const int s0 = t2 * 4;
        stepK<0>(lds, pB, afA, afB, pa, ((s0 + 1) & 63) * 32, sb, db, ((s0 + 2) & 63) * 32, acc);
        stepK<1>(lds, pB, afB, afA, pa, ((s0 + 2) & 63) * 32, sb, db, ((s0 + 3) & 63) * 32, acc);
        stepK<2>(lds, pB, afA, afB, pa, ((s0 + 3) & 63) * 32, sb, db, ((s0 + 4) & 63) * 32, acc);
        stepK<3>(lds, pB, afB, afA, pa, ((s0 + 4) & 63) * 32, sb, db, ((s0 + 5) & 63) * 32, acc);
    }
    asm volatile("s_waitcnt vmcnt(0)" ::: "memory");   // retire trailing DMA before exit

    // epilogue: D row (m) = kq*4 + reg, col (n) = lm  (verified 16x16 layout)
    const int cm0 = bm * 256 + wm * 128 + kq * 4;
    const int cn0 = bn * 256 + wn * 64 + lm;
#pragma unroll
    for (int mi = 0; mi < 8; ++mi)
#pragma unroll
        for (int ni = 0; ni < 4; ++ni) {
            float* cp = C + (size_t)(cm0 + mi * 16) * N_DIM + cn0 + ni * 16;
#pragma unroll
            for (int r = 0; r < 4; ++r) cp[(size_t)r * N_DIM] = acc[mi][ni][r];
        }
}

// ---------------- fp32 fallback (only if ws too small) ----------------

__global__ __launch_bounds__(256) void gemm_f32_fallback(const float* __restrict__ X,
                                                         const float* __restrict__ W,
                                                         float* __restrict__ C) {
    __shared__ float As2[16][64];
    __shared__ float Bs2[16][64];
    const int tid = threadIdx.x;
    const int bm = blockIdx.x & 31;
    const int bn = blockIdx.x >> 5;
    const int tm = tid & 15, tn = tid >> 4;
    float c[4][4] = {};
    for (int k0 = 0; k0 < K_DIM; k0 += 16) {
        __syncthreads();
#pragma unroll
        for (int i = 0; i < 4; ++i) {
            int e = i * 256 + tid;
            As2[e >> 6][e & 63] = W[(size_t)(k0 + (e >> 6)) * M_DIM + bm * 64 + (e & 63)];
        }
#pragma unroll
        for (int i = 0; i < 4; ++i) {
            int e = i * 256 + tid;
            Bs2[e & 15][e >> 4] = X[(size_t)(bn * 64 + (e >> 4)) * K_DIM + k0 + (e & 15)];
        }
        __syncthreads();
#pragma unroll
        for (int kk = 0; kk < 16; ++kk)
#pragma unroll
            for (int i = 0; i < 4; ++i)
#pragma unroll
                for (int j = 0; j < 4; ++j)
                    c[i][j] += As2[kk][tm * 4 + i] * Bs2[kk][tn * 4 + j];
    }
#pragma unroll
    for (int i = 0; i < 4; ++i)
#pragma unroll
        for (int j = 0; j < 4; ++j)
            C[(size_t)(bm * 64 + tm * 4 + i) * N_DIM + bn * 64 + tn * 4 + j] = c[i][j];
}

// ---------------- launch ----------------

extern "C" void kernel_launch(void* const* d_in, const int* in_sizes, int n_in,
                              void* d_out, int out_size, void* d_ws, size_t ws_size,
                              hipStream_t stream) {
    const float* X = (const float*)d_in[0];  // [8192, 2048]
    const float* W = (const float*)d_in[1];  // [2048, 2048]
    // d_in[2] = bias: intentionally unused (reference discards it)
    float* C = (float*)d_out;                // [2048, 8192]

    const size_t xb_bytes = (size_t)N_DIM * K_DIM * sizeof(_Float16);  // 32 MB
    const size_t wt_bytes = (size_t)M_DIM * K_DIM * sizeof(_Float16);  //  8 MB

    if (ws_size >= xb_bytes + wt_bytes) {
        static bool attr_set = false;
        if (!attr_set) {
            (void)hipFuncSetAttribute(reinterpret_cast<const void*>(gemm_f16_256),
                                      hipFuncAttributeMaxDynamicSharedMemorySize,
                                      65536);
            attr_set = true;
        }
        _Float16* Xb = (_Float16*)d_ws;
        _Float16* Wt = (_Float16*)((char*)d_ws + xb_bytes);
        prep<<<8192 + 4096, 256, 0, stream>>>(X, W, Xb, Wt);
        gemm_f16_256<<<(M_DIM / 256) * (N_DIM / 256), 512, 65536, stream>>>(Wt, Xb, C);
    } else {
        gemm_f32_fallback<<<(M_DIM / 64) * (N_DIM / 64), 256, 0, stream>>>(X, W, C);
    }
}

// Round 6
// 188.422 us; speedup vs baseline: 1.4966x; 1.4966x over previous
//
#include <hip/hip_runtime.h>
#include <stdint.h>

// Problem: out[M=2048(size_out), N=8192(batch)] = W[K,M]^T @ X[N,K]^T
//   out[m,n] = sum_k W[k,m] * X[n,k]
#define M_DIM 2048
#define N_DIM 8192
#define K_DIM 2048

typedef _Float16 f16x8 __attribute__((ext_vector_type(8)));
typedef _Float16 f16x4 __attribute__((ext_vector_type(4)));
typedef float    f32x4 __attribute__((ext_vector_type(4)));

// ---------------- fused prep: cvt X (blocks 0..8191) + transpose W (8192..12287) ----------------

__global__ __launch_bounds__(256) void prep(const float* __restrict__ X,
                                            const float* __restrict__ W,
                                            _Float16* __restrict__ Xb,
                                            _Float16* __restrict__ Wt) {
    __shared__ float tile[32][33];
    int b = blockIdx.x;
    if (b < 8192) {
        size_t i = ((size_t)b * 256 + threadIdx.x) * 8;
        float4 a = *(const float4*)(X + i);
        float4 c = *(const float4*)(X + i + 4);
        f16x8 h;
        h[0] = (_Float16)a.x; h[1] = (_Float16)a.y; h[2] = (_Float16)a.z; h[3] = (_Float16)a.w;
        h[4] = (_Float16)c.x; h[5] = (_Float16)c.y; h[6] = (_Float16)c.z; h[7] = (_Float16)c.w;
        *(f16x8*)(Xb + i) = h;
    } else {
        b -= 8192;
        const int m0 = (b & 63) * 32;
        const int k0 = (b >> 6) * 32;
        const int tx = threadIdx.x & 31;
        const int ty = threadIdx.x >> 5;
#pragma unroll
        for (int i = 0; i < 32; i += 8)
            tile[ty + i][tx] = W[(size_t)(k0 + ty + i) * M_DIM + m0 + tx];
        __syncthreads();
        const int ml = threadIdx.x >> 3;
        const int kg = (threadIdx.x & 7) * 4;
        f16x4 v;
#pragma unroll
        for (int j = 0; j < 4; ++j) v[j] = (_Float16)tile[kg + j][ml];
        *(f16x4*)(Wt + (size_t)(m0 + ml) * K_DIM + k0 + kg) = v;
    }
}

// ---------------- m201-faithful 256x256 f16 GEMM: quadrant phases, half-tile ring ----------------
//
// 8 waves 2Mx4N (wave tile 128x64), BK=64. LDS 128KB = A-ring 4 x 16KB + B-ring
// 4 x 16KB half-tile slots (slot = buf*2 + half).
// Row-PERMUTED halves (so each half has a single read phase across ALL waves):
//   A half qh: slot rows p = wm*64 + q  <-> global m-row wm*128 + qh*64 + q
//   B half v : slot rows p = wn*32 + q  <-> global n-row wn*64 + v*32 + q
// Per K-tile, 4 quadrant phases over the wave's 128x64 output (16 MFMA each):
//   Ph1 Q(qh0,v0): read af0(8)+bf(4)=12; stage B1(T+1);           last read of A0,B0
//   Ph2 Q(qh1,v0): read af1(8), bf cached; stage A0(T+2);         last read of A1
//   Ph3 Q(qh1,v1): read bf(4), af1 cached; stage B0(T+2);         last read of B1
//   Ph4 Q(qh0,v1): NO reads (af0+bf cached); stage A1(T+2); vmcnt(6)
// Each phase: {reads; stage; fence; barrier; lgkmcnt(0); setprio1; 16 MFMA;
// setprio0; barrier}. ONE counted vmcnt(6) per tile (at ph4): retires exactly
// tile T+1's 4 halves, leaves {A0,B0,A1}(T+2) = 3 halves = 6 loads in flight.
// Staging runs 1.5 tiles ahead; every stage issues >=1 phase after its slot's
// last read (post-barrier) -> no overwrite race. Counted waits only, no drain.
// Swizzle (HW-verified R1): slot chunk = c ^ (p&7) on 16B chunks of 128B rows;
// staging keeps linear LDS dest, inverse-swizzled global source
// cg = (tid&7)^((tid>>3)&7) (rule #21).

__device__ __forceinline__ void load_to_lds16(const void* g, void* l) {
    __builtin_amdgcn_global_load_lds(
        (__attribute__((address_space(1))) void*)(uintptr_t)g,
        (__attribute__((address_space(3))) void*)l,
        16, 0, 0);
}

// stage one permuted half (128 slot-rows x 128B = 16KB): j=0 -> slot rows 0-63,
// j=1 -> 64-127. s0/s1 = per-thread source for j=0/1 (already half-offset).
__device__ __forceinline__ void stage2(const _Float16* s0, const _Float16* s1, char* d) {
    load_to_lds16(s0, d);
    load_to_lds16(s1, d + 8192);
}

#define PH_PRE()  do { asm volatile("" ::: "memory"); \
                       __builtin_amdgcn_s_barrier(); \
                       asm volatile("s_waitcnt lgkmcnt(0)" ::: "memory"); \
                       __builtin_amdgcn_s_setprio(1); } while (0)
#define PH_POST() do { __builtin_amdgcn_s_setprio(0); \
                       __builtin_amdgcn_s_barrier(); } while (0)

template <int BUF>
__device__ __forceinline__ void tileQ(const char* lds, int pA, int pB,
                                      const _Float16* sA, const _Float16* sB,
                                      char* dAw, char* dBw, int kN, int kNN,
                                      f32x4 (&acc)[8][4]) {
    const char* A0s = lds + BUF * 32768;            // A slot (BUF, qh=0)
    const char* A1s = A0s + 16384;
    const char* B0s = lds + 65536 + BUF * 32768;    // B slot (BUF, v=0)
    const char* B1s = B0s + 16384;
    constexpr int NB = (BUF ^ 1) * 32768;
    constexpr int CB = BUF * 32768;

    f16x8 af0[4][2], af1[4][2], bf[2][2];

    // ---- Ph1: Q(qh0, v0) — 12 reads; stage B1(T+1) ----
#pragma unroll
    for (int n = 0; n < 2; ++n)
#pragma unroll
        for (int k = 0; k < 2; ++k)
            bf[n][k] = *(const f16x8*)(B0s + ((pB + n * 2048) ^ (k << 6)));
#pragma unroll
    for (int m = 0; m < 4; ++m)
#pragma unroll
        for (int k = 0; k < 2; ++k)
            af0[m][k] = *(const f16x8*)(A0s + ((pA + m * 2048) ^ (k << 6)));
    stage2(sB + (size_t)32 * K_DIM + kN, sB + (size_t)160 * K_DIM + kN, dBw + NB + 16384);
    PH_PRE();
#pragma unroll
    for (int m = 0; m < 4; ++m)
#pragma unroll
        for (int n = 0; n < 2; ++n)
#pragma unroll
            for (int k = 0; k < 2; ++k)
                acc[m][n] = __builtin_amdgcn_mfma_f32_16x16x32_f16(af0[m][k], bf[n][k], acc[m][n], 0, 0, 0);
    PH_POST();

    // ---- Ph2: Q(qh1, v0) — 8 reads (bf cached); stage A0(T+2) ----
#pragma unroll
    for (int m = 0; m < 4; ++m)
#pragma unroll
        for (int k = 0; k < 2; ++k)
            af1[m][k] = *(const f16x8*)(A1s + ((pA + m * 2048) ^ (k << 6)));
    stage2(sA + kNN, sA + (size_t)128 * K_DIM + kNN, dAw + CB);
    PH_PRE();
#pragma unroll
    for (int m = 0; m < 4; ++m)
#pragma unroll
        for (int n = 0; n < 2; ++n)
#pragma unroll
            for (int k = 0; k < 2; ++k)
                acc[4 + m][n] = __builtin_amdgcn_mfma_f32_16x16x32_f16(af1[m][k], bf[n][k], acc[4 + m][n], 0, 0, 0);
    PH_POST();

    // ---- Ph3: Q(qh1, v1) — 4 reads (af1 cached); stage B0(T+2) ----
#pragma unroll
    for (int n = 0; n < 2; ++n)
#pragma unroll
        for (int k = 0; k < 2; ++k)
            bf[n][k] = *(const f16x8*)(B1s + ((pB + n * 2048) ^ (k << 6)));
    stage2(sB + kNN, sB + (size_t)128 * K_DIM + kNN, dBw + CB);
    PH_PRE();
#pragma unroll
    for (int m = 0; m < 4; ++m)
#pragma unroll
        for (int n = 0; n < 2; ++n)
#pragma unroll
            for (int k = 0; k < 2; ++k)
                acc[4 + m][2 + n] = __builtin_amdgcn_mfma_f32_16x16x32_f16(af1[m][k], bf[n][k], acc[4 + m][2 + n], 0, 0, 0);
    PH_POST();

    // ---- Ph4: Q(qh0, v1) — 0 reads (af0+bf cached); stage A1(T+2); vmcnt(6) ----
    stage2(sA + (size_t)64 * K_DIM + kNN, sA + (size_t)192 * K_DIM + kNN, dAw + CB + 16384);
    asm volatile("s_waitcnt vmcnt(6)" ::: "memory");
    __builtin_amdgcn_s_barrier();
    __builtin_amdgcn_s_setprio(1);
#pragma unroll
    for (int m = 0; m < 4; ++m)
#pragma unroll
        for (int n = 0; n < 2; ++n)
#pragma unroll
            for (int k = 0; k < 2; ++k)
                acc[m][2 + n] = __builtin_amdgcn_mfma_f32_16x16x32_f16(af0[m][k], bf[n][k], acc[m][2 + n], 0, 0, 0);
    PH_POST();
}

// A = Wt [M,K] f16 (K-contiguous), B = Xb [N,K] f16 (K-contiguous), C [M,N] fp32
__global__ __launch_bounds__(512, 2) void gemm_f16_256(const _Float16* __restrict__ A,
                                                       const _Float16* __restrict__ B,
                                                       float* __restrict__ C) {
    extern __shared__ char lds[];          // 128KB: A-ring 4x16KB | B-ring 4x16KB

    const int tid  = threadIdx.x;
    const int wave = tid >> 6;
    const int lane = tid & 63;
    const int lm = lane & 15, kq = lane >> 4;
    const int wm = wave >> 2, wn = wave & 3;   // 2x4 wave grid, each 128x64 of C

    // XCD swizzle: XCD x owns bm = x (1MB A panel L2-resident) x all 32 bn
    const int bid = ((blockIdx.x & 7) << 5) | (blockIdx.x >> 3);
    const int bm = bid >> 5;               // 0..7
    const int bn = bid & 31;               // 0..31

    // staging source (per-thread): slot-row q8 = tid>>3, inverse-swizzled chunk
    const int q8 = tid >> 3;                              // 0..63
    const int cg = ((tid & 7) ^ (q8 & 7)) * 8;            // f16 elems
    // A: slot row p = j*64 + q8 -> global row j*128 + h*64 + q8 (h added per stage)
    const _Float16* sA = A + (size_t)(bm * 256 + q8) * K_DIM + cg;
    // B: slot row p = j*64 + q8 -> global row (j*2 + (q8>>5))*64 + v*32 + (q8&31)
    const _Float16* sB = B + (size_t)(bn * 256 + (q8 >> 5) * 64 + (q8 & 31)) * K_DIM + cg;
    char* dAw = lds + wave * 1024;             // + buf*32768 + h*16384 (+8192 j=1)
    char* dBw = lds + 65536 + wave * 1024;

    // fragment read offsets within a half-slot: row p, chunk (kk*4+kq)^(p&7);
    // p&7 = lm&7 (bases are 16-aligned) -> lane-constant swizzle
    const int pA = (wm * 64 + lm) * 128 + (kq ^ (lm & 7)) * 16;   // + mi*2048, ^(kk<<6)
    const int pB = (wn * 32 + lm) * 128 + (kq ^ (lm & 7)) * 16;   // + ni*2048, ^(kk<<6)

    f32x4 acc[8][4] = {};

    // prologue: stage A0,B0,A1,B1(tile0) + A0,B0,A1(tile1) = 7 halves (14 loads),
    // then vmcnt(6): tile0's 4 halves retired, tile1's 3 in flight (steady state).
    stage2(sA,                       sA + (size_t)128 * K_DIM,       dAw);            // A0(0)
    stage2(sB,                       sB + (size_t)128 * K_DIM,       dBw);            // B0(0)
    stage2(sA + (size_t)64 * K_DIM,  sA + (size_t)192 * K_DIM,       dAw + 16384);    // A1(0)
    stage2(sB + (size_t)32 * K_DIM,  sB + (size_t)160 * K_DIM,       dBw + 16384);    // B1(0)
    stage2(sA + 64,                  sA + (size_t)128 * K_DIM + 64,  dAw + 32768);            // A0(1)
    stage2(sB + 64,                  sB + (size_t)128 * K_DIM + 64,  dBw + 32768);            // B0(1)
    stage2(sA + (size_t)64 * K_DIM + 64, sA + (size_t)192 * K_DIM + 64, dAw + 32768 + 16384); // A1(1)
    asm volatile("s_waitcnt vmcnt(6)" ::: "memory");
    __builtin_amdgcn_s_barrier();

    // main loop: 32 K-tiles; tile T in buf T&1; stages B1(T+1), A0/B0/A1(T+2)
#pragma unroll 1
    for (int t2 = 0; t2 < 16; ++t2) {
        const int T = t2 * 2;
        tileQ<0>(lds, pA, pB, sA, sB, dAw, dBw,
                 ((T + 1) & 31) * 64, ((T + 2) & 31) * 64, acc);
        tileQ<1>(lds, pA, pB, sA, sB, dAw, dBw,
                 ((T + 2) & 31) * 64, ((T + 3) & 31) * 64, acc);
    }
    asm volatile("s_waitcnt vmcnt(0)" ::: "memory");   // retire trailing DMA

    // epilogue: D row (m) = kq*4 + reg, col (n) = lm  (verified 16x16 layout)
    // global mi = qh*4+(mi&3): rows wm*128 + mi*16; ni = v*2+(ni&1): cols wn*64 + ni*16
    const int cm0 = bm * 256 + wm * 128 + kq * 4;
    const int cn0 = bn * 256 + wn * 64 + lm;
#pragma unroll
    for (int mi = 0; mi < 8; ++mi)
#pragma unroll
        for (int ni = 0; ni < 4; ++ni) {
            const int mg = ((mi >> 2) ? 0 : 0) * 0 + mi;  // acc[mi] holds qh=(mi>>2), local (mi&3)
            const int row = cm0 + ((mi >> 2) * 4 + (mi & 3)) * 16;
            const int col = cn0 + ((ni >> 1) * 2 + (ni & 1)) * 16;
            (void)mg;
            float* cp = C + (size_t)row * N_DIM + col;
#pragma unroll
            for (int r = 0; r < 4; ++r) cp[(size_t)r * N_DIM] = acc[mi][ni][r];
        }
}

// ---------------- fp32 fallback (only if ws too small) ----------------

__global__ __launch_bounds__(256) void gemm_f32_fallback(const float* __restrict__ X,
                                                         const float* __restrict__ W,
                                                         float* __restrict__ C) {
    __shared__ float As2[16][64];
    __shared__ float Bs2[16][64];
    const int tid = threadIdx.x;
    const int bm = blockIdx.x & 31;
    const int bn = blockIdx.x >> 5;
    const int tm = tid & 15, tn = tid >> 4;
    float c[4][4] = {};
    for (int k0 = 0; k0 < K_DIM; k0 += 16) {
        __syncthreads();
#pragma unroll
        for (int i = 0; i < 4; ++i) {
            int e = i * 256 + tid;
            As2[e >> 6][e & 63] = W[(size_t)(k0 + (e >> 6)) * M_DIM + bm * 64 + (e & 63)];
        }
#pragma unroll
        for (int i = 0; i < 4; ++i) {
            int e = i * 256 + tid;
            Bs2[e & 15][e >> 4] = X[(size_t)(bn * 64 + (e >> 4)) * K_DIM + k0 + (e & 15)];
        }
        __syncthreads();
#pragma unroll
        for (int kk = 0; kk < 16; ++kk)
#pragma unroll
            for (int i = 0; i < 4; ++i)
#pragma unroll
                for (int j = 0; j < 4; ++j)
                    c[i][j] += As2[kk][tm * 4 + i] * Bs2[kk][tn * 4 + j];
    }
#pragma unroll
    for (int i = 0; i < 4; ++i)
#pragma unroll
        for (int j = 0; j < 4; ++j)
            C[(size_t)(bm * 64 + tm * 4 + i) * N_DIM + bn * 64 + tn * 4 + j] = c[i][j];
}

// ---------------- launch ----------------

extern "C" void kernel_launch(void* const* d_in, const int* in_sizes, int n_in,
                              void* d_out, int out_size, void* d_ws, size_t ws_size,
                              hipStream_t stream) {
    const float* X = (const float*)d_in[0];  // [8192, 2048]
    const float* W = (const float*)d_in[1];  // [2048, 2048]
    // d_in[2] = bias: intentionally unused (reference discards it)
    float* C = (float*)d_out;                // [2048, 8192]

    const size_t xb_bytes = (size_t)N_DIM * K_DIM * sizeof(_Float16);  // 32 MB
    const size_t wt_bytes = (size_t)M_DIM * K_DIM * sizeof(_Float16);  //  8 MB

    if (ws_size >= xb_bytes + wt_bytes) {
        static bool attr_set = false;
        if (!attr_set) {
            (void)hipFuncSetAttribute(reinterpret_cast<const void*>(gemm_f16_256),
                                      hipFuncAttributeMaxDynamicSharedMemorySize,
                                      131072);
            attr_set = true;
        }
        _Float16* Xb = (_Float16*)d_ws;
        _Float16* Wt = (_Float16*)((char*)d_ws + xb_bytes);
        prep<<<8192 + 4096, 256, 0, stream>>>(X, W, Xb, Wt);
        gemm_f16_256<<<(M_DIM / 256) * (N_DIM / 256), 512, 131072, stream>>>(Wt, Xb, C);
    } else {
        gemm_f32_fallback<<<(M_DIM / 64) * (N_DIM / 64), 256, 0, stream>>>(X, W, C);
    }
}

// Round 8
// 186.525 us; speedup vs baseline: 1.5118x; 1.0102x over previous
//
#include <hip/hip_runtime.h>
#include <stdint.h>

// Problem: out[M=2048(size_out), N=8192(batch)] = W[K,M]^T @ X[N,K]^T
//   out[m,n] = sum_k W[k,m] * X[n,k]
#define M_DIM 2048
#define N_DIM 8192
#define K_DIM 2048

typedef _Float16 f16x8 __attribute__((ext_vector_type(8)));
typedef _Float16 f16x4 __attribute__((ext_vector_type(4)));
typedef float    f32x4 __attribute__((ext_vector_type(4)));

// ---------------- fused prep: cvt X (blocks 0..8191) + transpose W (8192..12287) ----------------

__global__ __launch_bounds__(256) void prep(const float* __restrict__ X,
                                            const float* __restrict__ W,
                                            _Float16* __restrict__ Xb,
                                            _Float16* __restrict__ Wt) {
    __shared__ float tile[32][33];
    int b = blockIdx.x;
    if (b < 8192) {
        size_t i = ((size_t)b * 256 + threadIdx.x) * 8;
        float4 a = *(const float4*)(X + i);
        float4 c = *(const float4*)(X + i + 4);
        f16x8 h;
        h[0] = (_Float16)a.x; h[1] = (_Float16)a.y; h[2] = (_Float16)a.z; h[3] = (_Float16)a.w;
        h[4] = (_Float16)c.x; h[5] = (_Float16)c.y; h[6] = (_Float16)c.z; h[7] = (_Float16)c.w;
        *(f16x8*)(Xb + i) = h;
    } else {
        b -= 8192;
        const int m0 = (b & 63) * 32;
        const int k0 = (b >> 6) * 32;
        const int tx = threadIdx.x & 31;
        const int ty = threadIdx.x >> 5;
#pragma unroll
        for (int i = 0; i < 32; i += 8)
            tile[ty + i][tx] = W[(size_t)(k0 + ty + i) * M_DIM + m0 + tx];
        __syncthreads();
        const int ml = threadIdx.x >> 3;
        const int kg = (threadIdx.x & 7) * 4;
        f16x4 v;
#pragma unroll
        for (int j = 0; j < 4; ++j) v[j] = (_Float16)tile[kg + j][ml];
        *(f16x4*)(Wt + (size_t)(m0 + ml) * K_DIM + k0 + kg) = v;
    }
}

// ---------------- 256x256 f16 GEMM: quadrant phases, half-tile ring (R6 body) ----------------
//
// R1/R2/R3/R6 (four different sync schedules) all measured ~5400 cyc/K-tile:
// staging-inbound-bound at ~6-7 TB/s external (L3/HBM) — NOT schedule-bound.
// R7 change: XCD ownership flipped from bm-major to bn-major so the DOMINANT
// traffic (B, 256MB logical) becomes L2-resident instead of A (8MB logical).
//   XCD x owns bn in {4x..4x+3} x all 8 bm: per-XCD B working set = 4 x 1MB
//   (8 co-resident blocks share each bn panel via L2); A streams external.
//   Ideal external reads: A 8MB x 8 XCD + B 32MB x 1 = 96MB (was ~264MB).
// Kernel body byte-identical to R6 (best verified: 72us, 0 bank conflicts).
//
// Schedule recap (m201-faithful): 8 waves 2Mx4N (wave tile 128x64), BK=64.
// LDS 128KB = A-ring 4 x 16KB + B-ring 4 x 16KB half-tile slots.
// Row-PERMUTED halves (single read phase per half across all waves):
//   A half qh: slot rows p = wm*64 + q  <-> global m-row wm*128 + qh*64 + q
//   B half v : slot rows p = wn*32 + q  <-> global n-row wn*64 + v*32 + q
// Per K-tile, 4 quadrant phases (16 MFMA each):
//   Ph1 Q(qh0,v0): read af0(8)+bf(4); stage B1(T+1)
//   Ph2 Q(qh1,v0): read af1(8), bf cached; stage A0(T+2)
//   Ph3 Q(qh1,v1): read bf(4), af1 cached; stage B0(T+2)
//   Ph4 Q(qh0,v1): 0 reads (af0+bf cached); stage A1(T+2); vmcnt(6)
// ONE counted vmcnt(6) per tile; staging 1.5 tiles ahead; no drains.
// Swizzle (HW-verified): slot chunk = c ^ (p&7); linear LDS dest with
// inverse-swizzled global source cg = (tid&7)^((tid>>3)&7) (rule #21).

__device__ __forceinline__ void load_to_lds16(const void* g, void* l) {
    __builtin_amdgcn_global_load_lds(
        (__attribute__((address_space(1))) void*)(uintptr_t)g,
        (__attribute__((address_space(3))) void*)l,
        16, 0, 0);
}

__device__ __forceinline__ void stage2(const _Float16* s0, const _Float16* s1, char* d) {
    load_to_lds16(s0, d);
    load_to_lds16(s1, d + 8192);
}

#define PH_PRE()  do { asm volatile("" ::: "memory"); \
                       __builtin_amdgcn_s_barrier(); \
                       asm volatile("s_waitcnt lgkmcnt(0)" ::: "memory"); \
                       __builtin_amdgcn_s_setprio(1); } while (0)
#define PH_POST() do { __builtin_amdgcn_s_setprio(0); \
                       __builtin_amdgcn_s_barrier(); } while (0)

template <int BUF>
__device__ __forceinline__ void tileQ(const char* lds, int pA, int pB,
                                      const _Float16* sA, const _Float16* sB,
                                      char* dAw, char* dBw, int kN, int kNN,
                                      f32x4 (&acc)[8][4]) {
    const char* A0s = lds + BUF * 32768;            // A slot (BUF, qh=0)
    const char* A1s = A0s + 16384;
    const char* B0s = lds + 65536 + BUF * 32768;    // B slot (BUF, v=0)
    const char* B1s = B0s + 16384;
    constexpr int NB = (BUF ^ 1) * 32768;
    constexpr int CB = BUF * 32768;

    f16x8 af0[4][2], af1[4][2], bf[2][2];

    // ---- Ph1: Q(qh0, v0) — 12 reads; stage B1(T+1) ----
#pragma unroll
    for (int n = 0; n < 2; ++n)
#pragma unroll
        for (int k = 0; k < 2; ++k)
            bf[n][k] = *(const f16x8*)(B0s + ((pB + n * 2048) ^ (k << 6)));
#pragma unroll
    for (int m = 0; m < 4; ++m)
#pragma unroll
        for (int k = 0; k < 2; ++k)
            af0[m][k] = *(const f16x8*)(A0s + ((pA + m * 2048) ^ (k << 6)));
    stage2(sB + (size_t)32 * K_DIM + kN, sB + (size_t)160 * K_DIM + kN, dBw + NB + 16384);
    PH_PRE();
#pragma unroll
    for (int m = 0; m < 4; ++m)
#pragma unroll
        for (int n = 0; n < 2; ++n)
#pragma unroll
            for (int k = 0; k < 2; ++k)
                acc[m][n] = __builtin_amdgcn_mfma_f32_16x16x32_f16(af0[m][k], bf[n][k], acc[m][n], 0, 0, 0);
    PH_POST();

    // ---- Ph2: Q(qh1, v0) — 8 reads (bf cached); stage A0(T+2) ----
#pragma unroll
    for (int m = 0; m < 4; ++m)
#pragma unroll
        for (int k = 0; k < 2; ++k)
            af1[m][k] = *(const f16x8*)(A1s + ((pA + m * 2048) ^ (k << 6)));
    stage2(sA + kNN, sA + (size_t)128 * K_DIM + kNN, dAw + CB);
    PH_PRE();
#pragma unroll
    for (int m = 0; m < 4; ++m)
#pragma unroll
        for (int n = 0; n < 2; ++n)
#pragma unroll
            for (int k = 0; k < 2; ++k)
                acc[4 + m][n] = __builtin_amdgcn_mfma_f32_16x16x32_f16(af1[m][k], bf[n][k], acc[4 + m][n], 0, 0, 0);
    PH_POST();

    // ---- Ph3: Q(qh1, v1) — 4 reads (af1 cached); stage B0(T+2) ----
#pragma unroll
    for (int n = 0; n < 2; ++n)
#pragma unroll
        for (int k = 0; k < 2; ++k)
            bf[n][k] = *(const f16x8*)(B1s + ((pB + n * 2048) ^ (k << 6)));
    stage2(sB + kNN, sB + (size_t)128 * K_DIM + kNN, dBw + CB);
    PH_PRE();
#pragma unroll
    for (int m = 0; m < 4; ++m)
#pragma unroll
        for (int n = 0; n < 2; ++n)
#pragma unroll
            for (int k = 0; k < 2; ++k)
                acc[4 + m][2 + n] = __builtin_amdgcn_mfma_f32_16x16x32_f16(af1[m][k], bf[n][k], acc[4 + m][2 + n], 0, 0, 0);
    PH_POST();

    // ---- Ph4: Q(qh0, v1) — 0 reads (af0+bf cached); stage A1(T+2); vmcnt(6) ----
    stage2(sA + (size_t)64 * K_DIM + kNN, sA + (size_t)192 * K_DIM + kNN, dAw + CB + 16384);
    asm volatile("s_waitcnt vmcnt(6)" ::: "memory");
    __builtin_amdgcn_s_barrier();
    __builtin_amdgcn_s_setprio(1);
#pragma unroll
    for (int m = 0; m < 4; ++m)
#pragma unroll
        for (int n = 0; n < 2; ++n)
#pragma unroll
            for (int k = 0; k < 2; ++k)
                acc[m][2 + n] = __builtin_amdgcn_mfma_f32_16x16x32_f16(af0[m][k], bf[n][k], acc[m][2 + n], 0, 0, 0);
    PH_POST();
}

// A = Wt [M,K] f16 (K-contiguous), B = Xb [N,K] f16 (K-contiguous), C [M,N] fp32
__global__ __launch_bounds__(512, 2) void gemm_f16_256(const _Float16* __restrict__ A,
                                                       const _Float16* __restrict__ B,
                                                       float* __restrict__ C) {
    extern __shared__ char lds[];          // 128KB: A-ring 4x16KB | B-ring 4x16KB

    const int tid  = threadIdx.x;
    const int wave = tid >> 6;
    const int lane = tid & 63;
    const int lm = lane & 15, kq = lane >> 4;
    const int wm = wave >> 2, wn = wave & 3;   // 2x4 wave grid, each 128x64 of C

    // XCD swizzle v2 (bn-major): XCD x owns bn in {4x..4x+3} x all 8 bm.
    // B working set per XCD = 4 x 1MB (L2-capturable, 8 blocks share each
    // panel); A (8MB) streams. blockIdx round-robins XCDs (xcd = blockIdx&7).
    const int xcd   = blockIdx.x & 7;
    const int local = blockIdx.x >> 3;     // 0..31 within XCD
    const int bn = xcd * 4 + (local & 3);  // 0..31
    const int bm = local >> 2;             // 0..7

    // staging source (per-thread): slot-row q8 = tid>>3, inverse-swizzled chunk
    const int q8 = tid >> 3;                              // 0..63
    const int cg = ((tid & 7) ^ (q8 & 7)) * 8;            // f16 elems
    // A: slot row p = j*64 + q8 -> global row j*128 + h*64 + q8 (h added per stage)
    const _Float16* sA = A + (size_t)(bm * 256 + q8) * K_DIM + cg;
    // B: slot row p = j*64 + q8 -> global row (j*2 + (q8>>5))*64 + v*32 + (q8&31)
    const _Float16* sB = B + (size_t)(bn * 256 + (q8 >> 5) * 64 + (q8 & 31)) * K_DIM + cg;
    char* dAw = lds + wave * 1024;             // + buf*32768 + h*16384 (+8192 j=1)
    char* dBw = lds + 65536 + wave * 1024;

    // fragment read offsets within a half-slot: row p, chunk (kk*4+kq)^(p&7);
    // p&7 = lm&7 (bases are 16-aligned) -> lane-constant swizzle
    const int pA = (wm * 64 + lm) * 128 + (kq ^ (lm & 7)) * 16;   // + mi*2048, ^(kk<<6)
    const int pB = (wn * 32 + lm) * 128 + (kq ^ (lm & 7)) * 16;   // + ni*2048, ^(kk<<6)

    f32x4 acc[8][4] = {};

    // prologue: stage A0,B0,A1,B1(tile0) + A0,B0,A1(tile1) = 7 halves (14 loads),
    // then vmcnt(6): tile0's 4 halves retired, tile1's 3 in flight (steady state).
    stage2(sA,                       sA + (size_t)128 * K_DIM,       dAw);            // A0(0)
    stage2(sB,                       sB + (size_t)128 * K_DIM,       dBw);            // B0(0)
    stage2(sA + (size_t)64 * K_DIM,  sA + (size_t)192 * K_DIM,       dAw + 16384);    // A1(0)
    stage2(sB + (size_t)32 * K_DIM,  sB + (size_t)160 * K_DIM,       dBw + 16384);    // B1(0)
    stage2(sA + 64,                  sA + (size_t)128 * K_DIM + 64,  dAw + 32768);            // A0(1)
    stage2(sB + 64,                  sB + (size_t)128 * K_DIM + 64,  dBw + 32768);            // B0(1)
    stage2(sA + (size_t)64 * K_DIM + 64, sA + (size_t)192 * K_DIM + 64, dAw + 32768 + 16384); // A1(1)
    asm volatile("s_waitcnt vmcnt(6)" ::: "memory");
    __builtin_amdgcn_s_barrier();

    // main loop: 32 K-tiles; tile T in buf T&1; stages B1(T+1), A0/B0/A1(T+2)
#pragma unroll 1
    for (int t2 = 0; t2 < 16; ++t2) {
        const int T = t2 * 2;
        tileQ<0>(lds, pA, pB, sA, sB, dAw, dBw,
                 ((T + 1) & 31) * 64, ((T + 2) & 31) * 64, acc);
        tileQ<1>(lds, pA, pB, sA, sB, dAw, dBw,
                 ((T + 2) & 31) * 64, ((T + 3) & 31) * 64, acc);
    }
    asm volatile("s_waitcnt vmcnt(0)" ::: "memory");   // retire trailing DMA

    // epilogue: D row (m) = kq*4 + reg, col (n) = lm  (verified 16x16 layout)
    // acc[mi][ni]: rows wm*128 + mi*16 (qh=(mi>>2) folds in), cols wn*64 + ni*16
    const int cm0 = bm * 256 + wm * 128 + kq * 4;
    const int cn0 = bn * 256 + wn * 64 + lm;
#pragma unroll
    for (int mi = 0; mi < 8; ++mi)
#pragma unroll
        for (int ni = 0; ni < 4; ++ni) {
            float* cp = C + (size_t)(cm0 + mi * 16) * N_DIM + cn0 + ni * 16;
#pragma unroll
            for (int r = 0; r < 4; ++r) cp[(size_t)r * N_DIM] = acc[mi][ni][r];
        }
}

// ---------------- fp32 fallback (only if ws too small) ----------------

__global__ __launch_bounds__(256) void gemm_f32_fallback(const float* __restrict__ X,
                                                         const float* __restrict__ W,
                                                         float* __restrict__ C) {
    __shared__ float As2[16][64];
    __shared__ float Bs2[16][64];
    const int tid = threadIdx.x;
    const int bm = blockIdx.x & 31;
    const int bn = blockIdx.x >> 5;
    const int tm = tid & 15, tn = tid >> 4;
    float c[4][4] = {};
    for (int k0 = 0; k0 < K_DIM; k0 += 16) {
        __syncthreads();
#pragma unroll
        for (int i = 0; i < 4; ++i) {
            int e = i * 256 + tid;
            As2[e >> 6][e & 63] = W[(size_t)(k0 + (e >> 6)) * M_DIM + bm * 64 + (e & 63)];
        }
#pragma unroll
        for (int i = 0; i < 4; ++i) {
            int e = i * 256 + tid;
            Bs2[e & 15][e >> 4] = X[(size_t)(bn * 64 + (e >> 4)) * K_DIM + k0 + (e & 15)];
        }
        __syncthreads();
#pragma unroll
        for (int kk = 0; kk < 16; ++kk)
#pragma unroll
            for (int i = 0; i < 4; ++i)
#pragma unroll
                for (int j = 0; j < 4; ++j)
                    c[i][j] += As2[kk][tm * 4 + i] * Bs2[kk][tn * 4 + j];
    }
#pragma unroll
    for (int i = 0; i < 4; ++i)
#pragma unroll
        for (int j = 0; j < 4; ++j)
            C[(size_t)(bm * 64 + tm * 4 + i) * N_DIM + bn * 64 + tn * 4 + j] = c[i][j];
}

// ---------------- launch ----------------

extern "C" void kernel_launch(void* const* d_in, const int* in_sizes, int n_in,
                              void* d_out, int out_size, void* d_ws, size_t ws_size,
                              hipStream_t stream) {
    const float* X = (const float*)d_in[0];  // [8192, 2048]
    const float* W = (const float*)d_in[1];  // [2048, 2048]
    // d_in[2] = bias: intentionally unused (reference discards it)
    float* C = (float*)d_out;                // [2048, 8192]

    const size_t xb_bytes = (size_t)N_DIM * K_DIM * sizeof(_Float16);  // 32 MB
    const size_t wt_bytes = (size_t)M_DIM * K_DIM * sizeof(_Float16);  //  8 MB

    if (ws_size >= xb_bytes + wt_bytes) {
        static bool attr_set = false;
        if (!attr_set) {
            (void)hipFuncSetAttribute(reinterpret_cast<const void*>(gemm_f16_256),
                                      hipFuncAttributeMaxDynamicSharedMemorySize,
                                      131072);
            attr_set = true;
        }
        _Float16* Xb = (_Float16*)d_ws;
        _Float16* Wt = (_Float16*)((char*)d_ws + xb_bytes);
        prep<<<8192 + 4096, 256, 0, stream>>>(X, W, Xb, Wt);
        gemm_f16_256<<<(M_DIM / 256) * (N_DIM / 256), 512, 131072, stream>>>(Wt, Xb, C);
    } else {
        gemm_f32_fallback<<<(M_DIM / 64) * (N_DIM / 64), 256, 0, stream>>>(X, W, C);
    }
}